// Round 7
// baseline (465.141 us; speedup 1.0000x reference)
//
#include <hip/hip_runtime.h>
#include <hip/hip_bf16.h>
#include <math.h>

#define EPSF 1e-7f

typedef __attribute__((ext_vector_type(8))) short bhalf8;   // 8 bf16 (4 VGPRs)
typedef __attribute__((ext_vector_type(4))) float floatx4;  // MFMA acc

// ============================================================================
// conv1: x[1024,3,32,32] -> h1t[1024,225,128] bf16 (position-major, ic inner)
// R7: one block per image; weights staged in LDS once; all 128 oc per thread
// (kills 4x window re-load of the old (img, oc-tile) grid; 256B/thread store)
// ============================================================================
__global__ __launch_bounds__(256) void conv1_kernel(
    const float* __restrict__ x, const float* __restrict__ w,
    const float* __restrict__ bias, __hip_bfloat16* __restrict__ out)
{
  __shared__ float wl[3456];     // [128 oc][27 taps], contiguous copy
  __shared__ float bl[128];
  const int b = blockIdx.x;
  const int t = threadIdx.x;
  for (int i = t; i < 3456; i += 256) wl[i] = w[i];
  if (t < 128) bl[t] = bias[t];
  __syncthreads();
  if (t >= 225) return;
  const int py = t / 15, px = t % 15;
  const float* xb = x + b * 3072;
  float win[27];
#pragma unroll
  for (int c = 0; c < 3; ++c)
#pragma unroll
    for (int ky = 0; ky < 3; ++ky)
#pragma unroll
      for (int kx = 0; kx < 3; ++kx)
        win[c*9 + ky*3 + kx] = xb[c*1024 + (py*2 + ky)*32 + (px*2 + kx)];
#pragma unroll 1
  for (int oc0 = 0; oc0 < 128; oc0 += 32) {
    __hip_bfloat16 hv[32];
#pragma unroll
    for (int oc = 0; oc < 32; ++oc) {
      const float* wp = &wl[(oc0 + oc)*27];    // wave-uniform -> LDS broadcast
      float acc = bl[oc0 + oc];
#pragma unroll
      for (int q = 0; q < 27; ++q) acc = fmaf(win[q], wp[q], acc);
      hv[oc] = __float2bfloat16(fmaxf(acc, 0.f));
    }
    uint4* dst = (uint4*)&out[((size_t)b*225 + t)*128 + oc0];
    const uint4* src = (const uint4*)hv;
#pragma unroll
    for (int q = 0; q < 4; ++q) dst[q] = src[q];
  }
}

// ============================================================================
// wtrans2: conv2_w fp32 [oc][ic][5][5] -> Wt bf16 [oc][k], k = tap*128 + ic
// ============================================================================
__global__ __launch_bounds__(256) void wtrans_kernel(
    const float* __restrict__ w, __hip_bfloat16* __restrict__ wt)
{
  int i = blockIdx.x*256 + threadIdx.x;          // 819,200 total
  int oc = i / 3200, r = i - oc*3200;
  int tap = r >> 7, ic = r & 127;
  wt[i] = __float2bfloat16(w[(oc*128 + ic)*25 + tap]);
}

// ============================================================================
// wtrans3: conv3_w fp32 [oc][ic][5][5] -> Wt bf16 [oc][k], k = tap*256 + ic
// ============================================================================
__global__ __launch_bounds__(256) void wtrans3_kernel(
    const float* __restrict__ w, __hip_bfloat16* __restrict__ wt)
{
  int i = blockIdx.x*256 + threadIdx.x;          // 1,638,400 total
  int oc = i / 6400, r = i - oc*6400;
  int tap = r >> 8, ic = r & 255;
  wt[i] = __float2bfloat16(w[(oc*256 + ic)*25 + tap]);
}

// ============================================================================
// wtrans_caps: caps_w fp32 [i][o][k][j] -> cwt fp32 [i][o][j][k] (k contig)
// so u_hat dot-products read coalesced float4s: cwt[f*16 + k], f=i*160+o*16+j
// ============================================================================
__global__ __launch_bounds__(256) void wtrans_caps_kernel(
    const float* __restrict__ cw, float* __restrict__ cwt)
{
  int i2 = blockIdx.x*256 + threadIdx.x;         // 163,840 total
  int k  = i2 & 15, j = (i2 >> 4) & 15, io = i2 >> 8;
  cwt[i2] = cw[(io*16 + k)*16 + j];
}

// ============================================================================
// cast: fp32 -> bf16 elementwise (layout-preserving), for fc weights
// ============================================================================
__global__ __launch_bounds__(256) void cast_bf16_kernel(
    const float* __restrict__ src, __hip_bfloat16* __restrict__ dst, int n)
{
  int i = blockIdx.x*256 + threadIdx.x;
  if (i < n) dst[i] = __float2bfloat16(src[i]);
}

// ============================================================================
// conv2_mfma: h1t[1024,225,128]bf16 -> h2t[1024,36,256]bf16, 5x5 s2, ReLU
// M=72 (2 img), N=256, K=3200. 512 threads = 8 waves (2/SIMD).
// R7: A-fragment ds_reads software-pipelined one icq ahead (af[2][5], static
// indices after unroll) so MFMAs wait on loads issued ~50 cyc earlier.
// ============================================================================
__global__ __launch_bounds__(512) void conv2_mfma_kernel(
    const __hip_bfloat16* __restrict__ a,   // h1t [1024][225][128]
    const __hip_bfloat16* __restrict__ wt,  // Wt2 [256][3200]
    const float* __restrict__ bias,
    __hip_bfloat16* __restrict__ out)       // h2t [1024][36][256]
{
  __shared__ __align__(16) unsigned short Il[2*225*136];  // 122,400 B
  const int b0   = blockIdx.x * 2;
  const int t    = threadIdx.x;
  const int lane = t & 63;
  const int w    = t >> 6;        // 0..7
  const int n    = lane & 15;
  const int g    = lane >> 4;

  // B fragment: oc row = w*32 + nt*16 + n, k col = s*32 + g*8
  const char* gB = (const char*)(wt + (size_t)(w*32 + n)*3200 + g*8);

  bhalf8 bb[2][2];                      // [slot][nt] (static idx only)
#pragma unroll
  for (int nt = 0; nt < 2; ++nt) bb[0][nt] = *(const bhalf8*)(gB + nt*102400);
#pragma unroll
  for (int nt = 0; nt < 2; ++nt) bb[1][nt] = *(const bhalf8*)(gB + nt*102400 + 64);

  // ---- stage 2 images: [pix][128ic] -> LDS [pix][136], chunk-swizzled ----
  for (int i = t; i < 7200; i += 512) {
    int img = (i >= 3600);
    int r = i - img*3600;
    int p = r >> 4, c = r & 15;
    uint4 v = *(const uint4*)((const char*)a +
              (((size_t)(b0+img)*225 + p)*256 + c*16));
    int csw = (c + (p >> 1)) & 15;
    *(uint4*)((char*)Il + ((img*225 + p)*136 + csw*8)*2) = v;
  }

  // ---- per-lane M geometry ----
  int rowb[5], pixb[5];
#pragma unroll
  for (int mt = 0; mt < 5; ++mt) {
    int m  = mt*16 + n;
    int mm = (m < 72) ? m : 0;
    int img = (mm >= 36);
    int pos = mm - img*36;
    int py = pos/6, px = pos - py*6;
    pixb[mt] = 30*py + 2*px;
    rowb[mt] = img*225*136;
  }

  floatx4 acc[5][2];
#pragma unroll
  for (int mt = 0; mt < 5; ++mt)
#pragma unroll
    for (int nt = 0; nt < 2; ++nt)
      acc[mt][nt] = (floatx4){0.f, 0.f, 0.f, 0.f};

  __syncthreads();   // Il staged; the ONLY barrier

  int s = 0;
#pragma unroll 1
  for (int ky = 0; ky < 5; ++ky) {
#pragma unroll 1
    for (int kx = 0; kx < 5; ++kx) {
      const int dpix = ky*15 + kx;
      int prow[5], pq[5];
#pragma unroll
      for (int mt = 0; mt < 5; ++mt) {
        int p = pixb[mt] + dpix;
        prow[mt] = rowb[mt] + p*136;
        pq[mt]   = p >> 1;
      }
      bhalf8 af[2][5];
      // prime icq=0 fragments
#pragma unroll
      for (int mt = 0; mt < 5; ++mt) {
        int csw = (g + pq[mt]) & 15;
        af[0][mt] = *(const bhalf8*)((const char*)Il + (prow[mt] + csw*8)*2);
      }
#pragma unroll
      for (int icq = 0; icq < 4; ++icq) {
        const int scur = s + icq;
        // prefetch icq+1's A-fragments BEFORE consuming icq's (overlap)
        if (icq < 3) {
#pragma unroll
          for (int mt = 0; mt < 5; ++mt) {
            int csw = (((icq+1)*4 + g) + pq[mt]) & 15;
            af[(icq+1) & 1][mt] =
                *(const bhalf8*)((const char*)Il + (prow[mt] + csw*8)*2);
          }
        }
#pragma unroll
        for (int mt = 0; mt < 5; ++mt)
#pragma unroll
          for (int nt = 0; nt < 2; ++nt)
            acc[mt][nt] = __builtin_amdgcn_mfma_f32_16x16x32_bf16(
                af[icq & 1][mt], bb[icq & 1][nt], acc[mt][nt], 0, 0, 0);
        {
          const int spre = (scur + 2 <= 99) ? (scur + 2) : 98;
          const char* pB = gB + spre*64;
#pragma unroll
          for (int nt = 0; nt < 2; ++nt)
            bb[icq & 1][nt] = *(const bhalf8*)(pB + nt*102400);
        }
      }
      s += 4;
    }
  }

  // ---- epilogue: D row=g*4+r (m), col=n (oc). write bf16 [img][pos][oc] ----
  float bv[2];
#pragma unroll
  for (int nt = 0; nt < 2; ++nt) bv[nt] = bias[w*32 + nt*16 + n];
#pragma unroll
  for (int mt = 0; mt < 5; ++mt) {
#pragma unroll
    for (int r = 0; r < 4; ++r) {
      int m = mt*16 + g*4 + r;
      if (m < 72) {
        int img = (m >= 36);
        int pos = m - img*36;
        __hip_bfloat16* op = out + (((size_t)(b0+img)*36 + pos)*256 + w*32 + n);
#pragma unroll
        for (int nt = 0; nt < 2; ++nt)
          op[nt*16] = __float2bfloat16(fmaxf(acc[mt][nt][r] + bv[nt], 0.f));
      }
    }
  }
}

// ============================================================================
// conv3_mfma: h2t[1024,36,256]bf16 -> h3[1024,256,2,2]fp32, 5x5 s1, ReLU
// M=16 (4 img), N=256, K=6400. 512 threads = 8 waves; wave: 1 Mtile x 2 Nt.
// R7: same A-prefetch pipeline (one ip ahead).
// ============================================================================
__global__ __launch_bounds__(512) void conv3_mfma_kernel(
    const __hip_bfloat16* __restrict__ a,   // h2t [1024][36][256]
    const __hip_bfloat16* __restrict__ wt,  // Wt3 [256][6400]
    const float* __restrict__ bias,
    float* __restrict__ out)                // h3 [1024][256][4]
{
  __shared__ __align__(16) unsigned short Il[4*10072];    // 80,576 B
  const int b0   = blockIdx.x * 4;
  const int t    = threadIdx.x;
  const int lane = t & 63;
  const int w    = t >> 6;        // 0..7
  const int n    = lane & 15;
  const int g    = lane >> 4;

  const char* gB = (const char*)(wt + (size_t)(w*32 + n)*6400 + g*8);

  bhalf8 bb[2][2][2];                   // [slot][nt][h] (static idx only)
#pragma unroll
  for (int nt = 0; nt < 2; ++nt) {
    bb[0][nt][0] = *(const bhalf8*)(gB + nt*204800);
    bb[0][nt][1] = *(const bhalf8*)(gB + nt*204800 + 64);
    bb[1][nt][0] = *(const bhalf8*)(gB + nt*204800 + 128);
    bb[1][nt][1] = *(const bhalf8*)(gB + nt*204800 + 192);
  }

  // ---- stage 4 input images: [pix][256ic] -> LDS [pix][272pad] ----
  for (int i = t; i < 4608; i += 512) {
    int img = i / 1152, r = i - img*1152;
    int p = r >> 5, c = r & 31;
    uint4 v = *(const uint4*)((const char*)a +
              ((((size_t)(b0+img)*36 + p) << 9) + c*16));
    *(uint4*)((char*)Il + img*20144 + p*544 + c*16) = v;
  }

  int Abase;
  {
    int img = n >> 2, pos = n & 3;
    int py = pos >> 1, px = pos & 1;
    Abase = img*20144 + (py*6 + px)*544 + g*16;       // bytes
  }

  floatx4 acc[2];
#pragma unroll
  for (int nt = 0; nt < 2; ++nt) acc[nt] = (floatx4){0.f, 0.f, 0.f, 0.f};

  __syncthreads();   // the ONLY barrier

  int s = 0;
#pragma unroll 1
  for (int ky = 0; ky < 5; ++ky) {
#pragma unroll 1
    for (int kx = 0; kx < 5; ++kx) {
      const int tapoff = (ky*6 + kx) * 544;
      const char* ap = (const char*)Il + Abase + tapoff;
      bhalf8 afa[2], afb[2];
      afa[0] = *(const bhalf8*)(ap);
      afb[0] = *(const bhalf8*)(ap + 64);
#pragma unroll
      for (int ip = 0; ip < 4; ++ip) {
        const int scur = s + ip;
        if (ip < 3) {
          afa[(ip+1) & 1] = *(const bhalf8*)(ap + (ip+1)*128);
          afb[(ip+1) & 1] = *(const bhalf8*)(ap + (ip+1)*128 + 64);
        }
#pragma unroll
        for (int nt = 0; nt < 2; ++nt) {
          acc[nt] = __builtin_amdgcn_mfma_f32_16x16x32_bf16(
              afa[ip & 1], bb[ip & 1][nt][0], acc[nt], 0, 0, 0);
          acc[nt] = __builtin_amdgcn_mfma_f32_16x16x32_bf16(
              afb[ip & 1], bb[ip & 1][nt][1], acc[nt], 0, 0, 0);
        }
        {
          const int spre = (scur + 2 <= 99) ? (scur + 2) : 98;
          const char* pB = gB + spre*128;
#pragma unroll
          for (int nt = 0; nt < 2; ++nt) {
            bb[ip & 1][nt][0] = *(const bhalf8*)(pB + nt*204800);
            bb[ip & 1][nt][1] = *(const bhalf8*)(pB + nt*204800 + 64);
          }
        }
      }
      s += 4;
    }
  }

  // ---- epilogue ----
  float bv[2];
#pragma unroll
  for (int nt = 0; nt < 2; ++nt) bv[nt] = bias[w*32 + nt*16 + n];
#pragma unroll
  for (int r = 0; r < 4; ++r) {
    int m = g*4 + r;
    int img = m >> 2, pos = m & 3;
    float* op = out + (((size_t)(b0+img)*256 + w*32 + n)*4 + pos);
#pragma unroll
    for (int nt = 0; nt < 2; ++nt)
      op[nt*64] = fmaxf(acc[nt][r] + bv[nt], 0.f);
  }
}

// ============================================================================
// caps: squash -> u_hat -> 3x dynamic routing -> v_lengths + fused fc1
// R7: consumes transposed cwt (k contiguous) -> float4 coalesced u_hat loads
// ============================================================================
__global__ __launch_bounds__(256) void caps_kernel(
    const float* __restrict__ h3, const float* __restrict__ cwt,
    const float* __restrict__ cb, const int* __restrict__ y,
    const float* __restrict__ fc1w, const float* __restrict__ fc1b,
    float* __restrict__ vlen, __hip_bfloat16* __restrict__ h1f)
{
  __shared__ float prim[1024];     // [64][16]
  __shared__ float uh[10240];      // [64][10][16]
  __shared__ float bij[640];
  __shared__ float cij[640];
  __shared__ float vv[160];        // [10][16]
  const int b = blockIdx.x, t = threadIdx.x;
  {
    const int cap = t >> 2, part = t & 3;
    float4 h = *(const float4*)&h3[b*1024 + cap*16 + part*4];
    float d = h.x*h.x + h.y*h.y + h.z*h.z + h.w*h.w;
    d += __shfl_xor(d, 1);
    d += __shfl_xor(d, 2);
    float sc = d / (1.f + d) / sqrtf(d + EPSF);
    float4 o4 = make_float4(h.x*sc, h.y*sc, h.z*sc, h.w*sc);
    *(float4*)&prim[cap*16 + part*4] = o4;
  }
  for (int f = t; f < 640; f += 256) bij[f] = 0.f;
  __syncthreads();
  // u_hat[f] = dot16(prim[i], cwt[f*16..]), f = i*160 + o*16 + j
  for (int f = t; f < 10240; f += 256) {
    const int i = f / 160;
    const float4* wv = (const float4*)(cwt + (size_t)f*16);
    const float4* pv = (const float4*)(prim + i*16);
    float4 w0 = wv[0], w1 = wv[1], w2 = wv[2], w3 = wv[3];
    float4 p0 = pv[0], p1 = pv[1], p2 = pv[2], p3 = pv[3];
    float s = 0.f;
    s = fmaf(p0.x, w0.x, s); s = fmaf(p0.y, w0.y, s);
    s = fmaf(p0.z, w0.z, s); s = fmaf(p0.w, w0.w, s);
    s = fmaf(p1.x, w1.x, s); s = fmaf(p1.y, w1.y, s);
    s = fmaf(p1.z, w1.z, s); s = fmaf(p1.w, w1.w, s);
    s = fmaf(p2.x, w2.x, s); s = fmaf(p2.y, w2.y, s);
    s = fmaf(p2.z, w2.z, s); s = fmaf(p2.w, w2.w, s);
    s = fmaf(p3.x, w3.x, s); s = fmaf(p3.y, w3.y, s);
    s = fmaf(p3.z, w3.z, s); s = fmaf(p3.w, w3.w, s);
    uh[f] = s;
  }
  __syncthreads();
  for (int r = 0; r < 3; ++r) {
    if (t < 64) {
      float e[10];
      float mx = -1e30f;
#pragma unroll
      for (int o = 0; o < 10; ++o) { e[o] = bij[t*10 + o]; mx = fmaxf(mx, e[o]); }
      float sum = 0.f;
#pragma unroll
      for (int o = 0; o < 10; ++o) { e[o] = expf(e[o] - mx); sum += e[o]; }
      float inv = 1.f / sum;
#pragma unroll
      for (int o = 0; o < 10; ++o) cij[t*10 + o] = e[o] * inv;
    }
    __syncthreads();
    if (t < 160) {
      const int o = t >> 4;
      float s = cb[t];
      for (int i = 0; i < 64; ++i) s = fmaf(cij[i*10 + o], uh[i*160 + t], s);
      float d = s*s;
      d += __shfl_xor(d, 1); d += __shfl_xor(d, 2);
      d += __shfl_xor(d, 4); d += __shfl_xor(d, 8);
      float sc = d / (1.f + d) / sqrtf(d + EPSF);
      vv[t] = s * sc;
      if (r == 2 && (t & 15) == 0)
        vlen[b*10 + o] = sqrtf(sc*sc*d + EPSF);
    }
    __syncthreads();
    if (r < 2) {
      for (int f = t; f < 640; f += 256) {
        int i = f / 10, o = f % 10;
        const float* up = &uh[i*160 + o*16];
        const float* vp = &vv[o*16];
        float a = 0.f;
#pragma unroll
        for (int j = 0; j < 16; ++j) a = fmaf(up[j], vp[j], a);
        bij[f] += a;
      }
      __syncthreads();
    }
  }
  const int yb = y[b];
  const float* vy = &vv[yb*16];
  for (int nn = t; nn < 512; nn += 256) {
    const float* wr = fc1w + nn*160 + yb*16;
    float s = fc1b[nn];
#pragma unroll
    for (int k = 0; k < 16; ++k) s = fmaf(vy[k], wr[k], s);
    h1f[b*512 + nn] = __float2bfloat16(fmaxf(s, 0.f));
  }
}

// ============================================================================
// fc_mfma: out = act(A[M,K]bf16 @ W[N,K]bf16^T + bias). Pure-register GEMM,
// two statically-indexed register sets (R5 scratch-demotion lesson).
// ============================================================================
template<int ACT, int MT, int NT>
__global__ __launch_bounds__(256) void fc_mfma_kernel(
    const __hip_bfloat16* __restrict__ A,   // [M,K]
    const __hip_bfloat16* __restrict__ W,   // [N,K]
    const float* __restrict__ bias,
    void* __restrict__ outv, int M, int N, int K)
{
  const int t    = threadIdx.x;
  const int lane = t & 63;
  const int w    = t >> 6;
  const int wr   = w >> 1, wc = w & 1;
  const int n    = lane & 15, g = lane >> 4;
  const int m0   = blockIdx.x * (2*MT*16) + wr*(MT*16);
  const int n0   = blockIdx.y * (2*NT*16) + wc*(NT*16);
  const __hip_bfloat16* Ap = A + (size_t)(m0 + n)*K + g*8;
  const __hip_bfloat16* Wp = W + (size_t)(n0 + n)*K + g*8;
  const int steps = K >> 5;               // 32-k steps; even for K=512/1024

  bhalf8 aa0[MT], aa1[MT], bb0[NT], bb1[NT];
#pragma unroll
  for (int mt = 0; mt < MT; ++mt) {
    aa0[mt] = *(const bhalf8*)(Ap + (size_t)mt*16*K);
    aa1[mt] = *(const bhalf8*)(Ap + (size_t)mt*16*K + 32);
  }
#pragma unroll
  for (int nt = 0; nt < NT; ++nt) {
    bb0[nt] = *(const bhalf8*)(Wp + (size_t)nt*16*K);
    bb1[nt] = *(const bhalf8*)(Wp + (size_t)nt*16*K + 32);
  }

  floatx4 acc[MT][NT];
#pragma unroll
  for (int mt = 0; mt < MT; ++mt)
#pragma unroll
    for (int nt = 0; nt < NT; ++nt)
      acc[mt][nt] = (floatx4){0.f, 0.f, 0.f, 0.f};

#pragma unroll 1
  for (int s = 0; s < steps; s += 2) {
#pragma unroll
    for (int mt = 0; mt < MT; ++mt)
#pragma unroll
      for (int nt = 0; nt < NT; ++nt)
        acc[mt][nt] = __builtin_amdgcn_mfma_f32_16x16x32_bf16(
            aa0[mt], bb0[nt], acc[mt][nt], 0, 0, 0);
    {
      const int spre = (s + 2 < steps) ? (s + 2) : s;
#pragma unroll
      for (int mt = 0; mt < MT; ++mt)
        aa0[mt] = *(const bhalf8*)(Ap + (size_t)mt*16*K + spre*32);
#pragma unroll
      for (int nt = 0; nt < NT; ++nt)
        bb0[nt] = *(const bhalf8*)(Wp + (size_t)nt*16*K + spre*32);
    }
#pragma unroll
    for (int mt = 0; mt < MT; ++mt)
#pragma unroll
      for (int nt = 0; nt < NT; ++nt)
        acc[mt][nt] = __builtin_amdgcn_mfma_f32_16x16x32_bf16(
            aa1[mt], bb1[nt], acc[mt][nt], 0, 0, 0);
    {
      const int spre = (s + 3 < steps) ? (s + 3) : (s + 1);
#pragma unroll
      for (int mt = 0; mt < MT; ++mt)
        aa1[mt] = *(const bhalf8*)(Ap + (size_t)mt*16*K + spre*32);
#pragma unroll
      for (int nt = 0; nt < NT; ++nt)
        bb1[nt] = *(const bhalf8*)(Wp + (size_t)nt*16*K + spre*32);
    }
  }

  // epilogue: D row = g*4+r, col = n
#pragma unroll
  for (int mt = 0; mt < MT; ++mt) {
#pragma unroll
    for (int r = 0; r < 4; ++r) {
      const int m = m0 + mt*16 + g*4 + r;
#pragma unroll
      for (int nt = 0; nt < NT; ++nt) {
        const int col = n0 + nt*16 + n;
        float v = acc[mt][nt][r] + bias[col];
        if (ACT == 0) {
          ((__hip_bfloat16*)outv)[(size_t)m*N + col] =
              __float2bfloat16(fmaxf(v, 0.f));
        } else {
          ((float*)outv)[(size_t)m*N + col] = 1.f / (1.f + expf(-v));
        }
      }
    }
  }
}

// ============================================================================
extern "C" void kernel_launch(void* const* d_in, const int* in_sizes, int n_in,
                              void* d_out, int out_size, void* d_ws, size_t ws_size,
                              hipStream_t stream) {
  const float* x       = (const float*)d_in[0];
  const int*   y       = (const int*)  d_in[1];
  const float* conv1_w = (const float*)d_in[2];
  const float* conv1_b = (const float*)d_in[3];
  const float* conv2_w = (const float*)d_in[4];
  const float* conv2_b = (const float*)d_in[5];
  const float* conv3_w = (const float*)d_in[6];
  const float* conv3_b = (const float*)d_in[7];
  const float* caps_w  = (const float*)d_in[8];
  const float* caps_b  = (const float*)d_in[9];
  const float* fc1_w   = (const float*)d_in[10];
  const float* fc1_b   = (const float*)d_in[11];
  const float* fc2_w   = (const float*)d_in[12];
  const float* fc2_b   = (const float*)d_in[13];
  const float* fc3_w   = (const float*)d_in[14];
  const float* fc3_b   = (const float*)d_in[15];
  float* out = (float*)d_out;
  float* ws  = (float*)d_ws;

  // ws layout (float units), total 24,526,848 floats = 98.1 MB
  __hip_bfloat16* h1t = (__hip_bfloat16*)ws;                 // 29,491,200 bf16
  __hip_bfloat16* wt2 = (__hip_bfloat16*)(ws + 14745600);    //    819,200 bf16
  __hip_bfloat16* wt3 = (__hip_bfloat16*)(ws + 15155200);    //  1,638,400 bf16
  __hip_bfloat16* h2t = (__hip_bfloat16*)(ws + 15974400);    //  9,437,184 bf16
  float*          h3c = ws + 20692992;                       //  1,048,576 f32
  __hip_bfloat16* h1f = (__hip_bfloat16*)(ws + 21741568);    //    524,288 bf16
  __hip_bfloat16* h2f = (__hip_bfloat16*)(ws + 22003712);    //  1,048,576 bf16
  __hip_bfloat16* wf2 = (__hip_bfloat16*)(ws + 22528000);    //    524,288 bf16
  __hip_bfloat16* wf3 = (__hip_bfloat16*)(ws + 22790144);    //  3,145,728 bf16
  float*          cwt = ws + 24363008;                       //    163,840 f32

  wtrans_kernel     <<<dim3(3200),  256, 0, stream>>>(conv2_w, wt2);
  wtrans3_kernel    <<<dim3(6400),  256, 0, stream>>>(conv3_w, wt3);
  wtrans_caps_kernel<<<dim3(640),   256, 0, stream>>>(caps_w, cwt);
  cast_bf16_kernel  <<<dim3(2048),  256, 0, stream>>>(fc2_w, wf2, 524288);
  cast_bf16_kernel  <<<dim3(12288), 256, 0, stream>>>(fc3_w, wf3, 3145728);
  conv1_kernel<<<dim3(1024),      256, 0, stream>>>(x, conv1_w, conv1_b, h1t);
  conv2_mfma_kernel<<<dim3(512),  512, 0, stream>>>(h1t, wt2, conv2_b, h2t);
  conv3_mfma_kernel<<<dim3(256),  512, 0, stream>>>(h2t, wt3, conv3_b, h3c);
  caps_kernel<<<dim3(1024),       256, 0, stream>>>(h3c, cwt, caps_b, y,
                                                    fc1_w, fc1_b, out, h1f);
  fc_mfma_kernel<0,2,2><<<dim3(16, 16), 256, 0, stream>>>(
      h1f, wf2, fc2_b, h2f, 1024, 1024, 512);
  fc_mfma_kernel<1,4,4><<<dim3(8, 24),  256, 0, stream>>>(
      h2f, wf3, fc3_b, out + 10240, 1024, 3072, 1024);
}

// Round 8
// 422.359 us; speedup vs baseline: 1.1013x; 1.1013x over previous
//
#include <hip/hip_runtime.h>
#include <hip/hip_bf16.h>
#include <math.h>

#define EPSF 1e-7f

typedef __attribute__((ext_vector_type(8))) short bhalf8;   // 8 bf16 (4 VGPRs)
typedef __attribute__((ext_vector_type(4))) float floatx4;  // MFMA acc

// ============================================================================
// conv1: x[1024,3,32,32] -> h1t[1024,225,128] bf16 (position-major, ic inner)
// ============================================================================
__global__ __launch_bounds__(256) void conv1_kernel(
    const float* __restrict__ x, const float* __restrict__ w,
    const float* __restrict__ bias, __hip_bfloat16* __restrict__ out)
{
  __shared__ float wl[3456];     // [128 oc][27 taps]
  __shared__ float bl[128];
  const int b = blockIdx.x;
  const int t = threadIdx.x;
  for (int i = t; i < 3456; i += 256) wl[i] = w[i];
  if (t < 128) bl[t] = bias[t];
  __syncthreads();
  if (t >= 225) return;
  const int py = t / 15, px = t % 15;
  const float* xb = x + b * 3072;
  float win[27];
#pragma unroll
  for (int c = 0; c < 3; ++c)
#pragma unroll
    for (int ky = 0; ky < 3; ++ky)
#pragma unroll
      for (int kx = 0; kx < 3; ++kx)
        win[c*9 + ky*3 + kx] = xb[c*1024 + (py*2 + ky)*32 + (px*2 + kx)];
#pragma unroll 1
  for (int oc0 = 0; oc0 < 128; oc0 += 32) {
    __hip_bfloat16 hv[32];
#pragma unroll
    for (int oc = 0; oc < 32; ++oc) {
      const float* wp = &wl[(oc0 + oc)*27];
      float acc = bl[oc0 + oc];
#pragma unroll
      for (int q = 0; q < 27; ++q) acc = fmaf(win[q], wp[q], acc);
      hv[oc] = __float2bfloat16(fmaxf(acc, 0.f));
    }
    uint4* dst = (uint4*)&out[((size_t)b*225 + t)*128 + oc0];
    const uint4* src = (const uint4*)hv;
#pragma unroll
    for (int q = 0; q < 4; ++q) dst[q] = src[q];
  }
}

// ============================================================================
// wtrans2: conv2_w -> DENSE step-major bf16: wt2[s][oc][kq], s=32-k step.
// idx = s*8192 + oc*32 + kq ; k = s*32+kq ; tap = k>>7 ; ic = k&127
// -> each wave B-load is 1KB fully contiguous (R8: halves TCP traffic)
// ============================================================================
__global__ __launch_bounds__(256) void wtrans_kernel(
    const float* __restrict__ w, __hip_bfloat16* __restrict__ wt)
{
  int i = blockIdx.x*256 + threadIdx.x;          // 819,200 total
  int s = i >> 13, r = i & 8191;
  int oc = r >> 5, kq = r & 31;
  int k = s*32 + kq;
  int tap = k >> 7, ic = k & 127;
  wt[i] = __float2bfloat16(w[(oc*128 + ic)*25 + tap]);
}

// ============================================================================
// wtrans3: conv3_w -> DENSE step-major bf16: wt3[s][oc][kq], s=64-k step.
// idx = s*16384 + oc*64 + kq ; k = s*64+kq ; tap = k>>8 ; ic = k&255
// ============================================================================
__global__ __launch_bounds__(256) void wtrans3_kernel(
    const float* __restrict__ w, __hip_bfloat16* __restrict__ wt)
{
  int i = blockIdx.x*256 + threadIdx.x;          // 1,638,400 total
  int s = i >> 14, r = i & 16383;
  int oc = r >> 6, kq = r & 63;
  int k = s*64 + kq;
  int tap = k >> 8, ic = k & 255;
  wt[i] = __float2bfloat16(w[(oc*256 + ic)*25 + tap]);
}

// ============================================================================
// wtrans_caps: caps_w fp32 [i][o][k][j] -> cwt BF16 [i][o][j][k] (k contig)
// ============================================================================
__global__ __launch_bounds__(256) void wtrans_caps_kernel(
    const float* __restrict__ cw, __hip_bfloat16* __restrict__ cwt)
{
  int i2 = blockIdx.x*256 + threadIdx.x;         // 163,840 total
  int k  = i2 & 15, j = (i2 >> 4) & 15, io = i2 >> 8;
  cwt[i2] = __float2bfloat16(cw[(io*16 + k)*16 + j]);
}

// ============================================================================
// wtrans_fc1: fc1_w [512][160] -> fc1wt [160][512] (coalesced caps epilogue)
// ============================================================================
__global__ __launch_bounds__(256) void wtrans_fc1_kernel(
    const float* __restrict__ w, float* __restrict__ wt)
{
  int i = blockIdx.x*256 + threadIdx.x;          // 81,920 total
  int j = i >> 9, n = i & 511;
  wt[i] = w[n*160 + j];
}

// ============================================================================
// cast: fp32 -> bf16 elementwise, for fc weights
// ============================================================================
__global__ __launch_bounds__(256) void cast_bf16_kernel(
    const float* __restrict__ src, __hip_bfloat16* __restrict__ dst, int n)
{
  int i = blockIdx.x*256 + threadIdx.x;
  if (i < n) dst[i] = __float2bfloat16(src[i]);
}

// ============================================================================
// conv2_mfma: h1t[1024,225,128]bf16 -> h2t[1024,36,256]bf16, 5x5 s2, ReLU
// M=72 (2 img), N=256, K=3200. 512 thr = 8 waves (2/SIMD). No K-loop barrier.
// R8: dense wt2 (1KB coalesced B loads), distance-4 B prefetch (4 static
// slots), A swizzle slot=(c+(p>>1)+(p>>5))&15 -> max 2-way (free) LDS reads.
// ============================================================================
__global__ __launch_bounds__(512) void conv2_mfma_kernel(
    const __hip_bfloat16* __restrict__ a,   // h1t [1024][225][128]
    const __hip_bfloat16* __restrict__ wt,  // wt2 dense [100][256][32]
    const float* __restrict__ bias,
    __hip_bfloat16* __restrict__ out)       // h2t [1024][36][256]
{
  __shared__ __align__(16) unsigned short Il[2*225*136];  // 122,400 B
  const int b0   = blockIdx.x * 2;
  const int t    = threadIdx.x;
  const int lane = t & 63;
  const int w    = t >> 6;        // 0..7
  const int n    = lane & 15;
  const int g    = lane >> 4;

  // B frag (nt, s): gB + s*16384 + nt*1024 bytes (wave covers 1KB contig)
  const char* gB = (const char*)wt + (size_t)(w*32 + n)*64 + g*16;

  bhalf8 bb[4][2];                      // [slot=s&3][nt] (static idx only)
#pragma unroll
  for (int ss = 0; ss < 4; ++ss)
#pragma unroll
    for (int nt = 0; nt < 2; ++nt)
      bb[ss][nt] = *(const bhalf8*)(gB + ss*16384 + nt*1024);

  // ---- stage 2 images: chunk c of pixel p -> slot (c + p/2 + p/32)&15 ----
  for (int i = t; i < 7200; i += 512) {
    int img = (i >= 3600);
    int r = i - img*3600;
    int p = r >> 4, c = r & 15;
    uint4 v = *(const uint4*)((const char*)a +
              (((size_t)(b0+img)*225 + p)*256 + c*16));
    int csw = (c + (p >> 1) + (p >> 5)) & 15;
    *(uint4*)((char*)Il + ((img*225 + p)*136 + csw*8)*2) = v;
  }

  // ---- per-lane M geometry ----
  int rowb[5], pixb[5];
#pragma unroll
  for (int mt = 0; mt < 5; ++mt) {
    int m  = mt*16 + n;
    int mm = (m < 72) ? m : 0;
    int img = (mm >= 36);
    int pos = mm - img*36;
    int py = pos/6, px = pos - py*6;
    pixb[mt] = 30*py + 2*px;
    rowb[mt] = img*225*136;
  }

  floatx4 acc[5][2];
#pragma unroll
  for (int mt = 0; mt < 5; ++mt)
#pragma unroll
    for (int nt = 0; nt < 2; ++nt)
      acc[mt][nt] = (floatx4){0.f, 0.f, 0.f, 0.f};

  __syncthreads();   // Il staged; the ONLY barrier

  int s = 0;
#pragma unroll 1
  for (int ky = 0; ky < 5; ++ky) {
#pragma unroll 1
    for (int kx = 0; kx < 5; ++kx) {
      const int dpix = ky*15 + kx;
      int prow[5], pqv[5];
#pragma unroll
      for (int mt = 0; mt < 5; ++mt) {
        int p = pixb[mt] + dpix;
        prow[mt] = rowb[mt] + p*136;
        pqv[mt]  = (p >> 1) + (p >> 5);
      }
      bhalf8 af[2][5];
#pragma unroll
      for (int mt = 0; mt < 5; ++mt) {
        int csw = (g + pqv[mt]) & 15;
        af[0][mt] = *(const bhalf8*)((const char*)Il + (prow[mt] + csw*8)*2);
      }
#pragma unroll
      for (int icq = 0; icq < 4; ++icq) {
        const int scur = s + icq;
        if (icq < 3) {
#pragma unroll
          for (int mt = 0; mt < 5; ++mt) {
            int csw = (((icq+1)*4 + g) + pqv[mt]) & 15;
            af[(icq+1) & 1][mt] =
                *(const bhalf8*)((const char*)Il + (prow[mt] + csw*8)*2);
          }
        }
#pragma unroll
        for (int mt = 0; mt < 5; ++mt)
#pragma unroll
          for (int nt = 0; nt < 2; ++nt)
            acc[mt][nt] = __builtin_amdgcn_mfma_f32_16x16x32_bf16(
                af[icq & 1][mt], bb[icq][nt], acc[mt][nt], 0, 0, 0);
        {
          const int spre = (scur + 4 <= 99) ? (scur + 4) : 99;
          const char* pB = gB + spre*16384;
#pragma unroll
          for (int nt = 0; nt < 2; ++nt)
            bb[icq][nt] = *(const bhalf8*)(pB + nt*1024);
        }
      }
      s += 4;
    }
  }

  // ---- epilogue: D row=g*4+r (m), col=n (oc). write bf16 [img][pos][oc] ----
  float bv[2];
#pragma unroll
  for (int nt = 0; nt < 2; ++nt) bv[nt] = bias[w*32 + nt*16 + n];
#pragma unroll
  for (int mt = 0; mt < 5; ++mt) {
#pragma unroll
    for (int r = 0; r < 4; ++r) {
      int m = mt*16 + g*4 + r;
      if (m < 72) {
        int img = (m >= 36);
        int pos = m - img*36;
        __hip_bfloat16* op = out + (((size_t)(b0+img)*36 + pos)*256 + w*32 + n);
#pragma unroll
        for (int nt = 0; nt < 2; ++nt)
          op[nt*16] = __float2bfloat16(fmaxf(acc[mt][nt][r] + bv[nt], 0.f));
      }
    }
  }
}

// ============================================================================
// conv3_mfma: h2t[1024,36,256]bf16 -> h3[1024,256,2,2]fp32, 5x5 s1, ReLU
// M=16 (4 img), N=256, K=6400. 512 thr = 8 waves. Dense wt3, distance-4 B.
// (A-read bank pattern verified exactly 2-way = free with 20144B img stride)
// ============================================================================
__global__ __launch_bounds__(512) void conv3_mfma_kernel(
    const __hip_bfloat16* __restrict__ a,   // h2t [1024][36][256]
    const __hip_bfloat16* __restrict__ wt,  // wt3 dense [100][256][64]
    const float* __restrict__ bias,
    float* __restrict__ out)                // h3 [1024][256][4]
{
  __shared__ __align__(16) unsigned short Il[4*10072];    // 80,576 B
  const int b0   = blockIdx.x * 4;
  const int t    = threadIdx.x;
  const int lane = t & 63;
  const int w    = t >> 6;        // 0..7
  const int n    = lane & 15;
  const int g    = lane >> 4;

  // B frag (nt, h, s): gB + s*32768 + nt*2048 + h*64 bytes
  const char* gB = (const char*)wt + (size_t)(w*32 + n)*128 + g*16;

  bhalf8 bb[4][2][2];                   // [slot][nt][h] (static idx only)
#pragma unroll
  for (int ss = 0; ss < 4; ++ss)
#pragma unroll
    for (int nt = 0; nt < 2; ++nt) {
      bb[ss][nt][0] = *(const bhalf8*)(gB + ss*32768 + nt*2048);
      bb[ss][nt][1] = *(const bhalf8*)(gB + ss*32768 + nt*2048 + 64);
    }

  // ---- stage 4 input images: [pix][256ic] -> LDS [pix][272pad] ----
  for (int i = t; i < 4608; i += 512) {
    int img = i / 1152, r = i - img*1152;
    int p = r >> 5, c = r & 31;
    uint4 v = *(const uint4*)((const char*)a +
              ((((size_t)(b0+img)*36 + p) << 9) + c*16));
    *(uint4*)((char*)Il + img*20144 + p*544 + c*16) = v;
  }

  int Abase;
  {
    int img = n >> 2, pos = n & 3;
    int py = pos >> 1, px = pos & 1;
    Abase = img*20144 + (py*6 + px)*544 + g*16;       // bytes
  }

  floatx4 acc[2];
#pragma unroll
  for (int nt = 0; nt < 2; ++nt) acc[nt] = (floatx4){0.f, 0.f, 0.f, 0.f};

  __syncthreads();   // the ONLY barrier

  int s = 0;
#pragma unroll 1
  for (int ky = 0; ky < 5; ++ky) {
#pragma unroll 1
    for (int kx = 0; kx < 5; ++kx) {
      const int tapoff = (ky*6 + kx) * 544;
      const char* ap = (const char*)Il + Abase + tapoff;
      bhalf8 afa[2], afb[2];
      afa[0] = *(const bhalf8*)(ap);
      afb[0] = *(const bhalf8*)(ap + 64);
#pragma unroll
      for (int ip = 0; ip < 4; ++ip) {
        const int scur = s + ip;
        if (ip < 3) {
          afa[(ip+1) & 1] = *(const bhalf8*)(ap + (ip+1)*128);
          afb[(ip+1) & 1] = *(const bhalf8*)(ap + (ip+1)*128 + 64);
        }
#pragma unroll
        for (int nt = 0; nt < 2; ++nt) {
          acc[nt] = __builtin_amdgcn_mfma_f32_16x16x32_bf16(
              afa[ip & 1], bb[ip][nt][0], acc[nt], 0, 0, 0);
          acc[nt] = __builtin_amdgcn_mfma_f32_16x16x32_bf16(
              afb[ip & 1], bb[ip][nt][1], acc[nt], 0, 0, 0);
        }
        {
          const int spre = (scur + 4 <= 99) ? (scur + 4) : 99;
          const char* pB = gB + spre*32768;
#pragma unroll
          for (int nt = 0; nt < 2; ++nt) {
            bb[ip][nt][0] = *(const bhalf8*)(pB + nt*2048);
            bb[ip][nt][1] = *(const bhalf8*)(pB + nt*2048 + 64);
          }
        }
      }
      s += 4;
    }
  }

  // ---- epilogue ----
  float bv[2];
#pragma unroll
  for (int nt = 0; nt < 2; ++nt) bv[nt] = bias[w*32 + nt*16 + n];
#pragma unroll
  for (int r = 0; r < 4; ++r) {
    int m = g*4 + r;
    int img = m >> 2, pos = m & 3;
    float* op = out + (((size_t)(b0+img)*256 + w*32 + n)*4 + pos);
#pragma unroll
    for (int nt = 0; nt < 2; ++nt)
      op[nt*64] = fmaxf(acc[nt][r] + bv[nt], 0.f);
  }
}

// ============================================================================
// caps: squash -> u_hat -> 3x routing -> v_lengths + fused fc1
// R8: bf16 cwt (halves the 655MB L2 stream), transposed fc1wt (coalesced)
// ============================================================================
__global__ __launch_bounds__(256) void caps_kernel(
    const float* __restrict__ h3, const __hip_bfloat16* __restrict__ cwt,
    const float* __restrict__ cb, const int* __restrict__ y,
    const float* __restrict__ fc1wt, const float* __restrict__ fc1b,
    float* __restrict__ vlen, __hip_bfloat16* __restrict__ h1f)
{
  __shared__ float prim[1024];     // [64][16]
  __shared__ float uh[10240];      // [64][10][16]
  __shared__ float bij[640];
  __shared__ float cij[640];
  __shared__ float vv[160];        // [10][16]
  const int b = blockIdx.x, t = threadIdx.x;
  {
    const int cap = t >> 2, part = t & 3;
    float4 h = *(const float4*)&h3[b*1024 + cap*16 + part*4];
    float d = h.x*h.x + h.y*h.y + h.z*h.z + h.w*h.w;
    d += __shfl_xor(d, 1);
    d += __shfl_xor(d, 2);
    float sc = d / (1.f + d) / sqrtf(d + EPSF);
    float4 o4 = make_float4(h.x*sc, h.y*sc, h.z*sc, h.w*sc);
    *(float4*)&prim[cap*16 + part*4] = o4;
  }
  for (int f = t; f < 640; f += 256) bij[f] = 0.f;
  __syncthreads();
  // u_hat[f] = dot16(prim[i], cwt[f*16..]) with bf16 weights expanded inline
  for (int f = t; f < 10240; f += 256) {
    const int i = f / 160;
    const uint4* wv = (const uint4*)(cwt + (size_t)f*16);
    uint4 wa = wv[0], wb = wv[1];
    unsigned uw[8] = {wa.x, wa.y, wa.z, wa.w, wb.x, wb.y, wb.z, wb.w};
    const float* pp = prim + i*16;
    float s = 0.f;
#pragma unroll
    for (int q = 0; q < 8; ++q) {
      float lo = __uint_as_float(uw[q] << 16);
      float hi = __uint_as_float(uw[q] & 0xffff0000u);
      s = fmaf(pp[2*q],   lo, s);
      s = fmaf(pp[2*q+1], hi, s);
    }
    uh[f] = s;
  }
  __syncthreads();
  for (int r = 0; r < 3; ++r) {
    if (t < 64) {
      float e[10];
      float mx = -1e30f;
#pragma unroll
      for (int o = 0; o < 10; ++o) { e[o] = bij[t*10 + o]; mx = fmaxf(mx, e[o]); }
      float sum = 0.f;
#pragma unroll
      for (int o = 0; o < 10; ++o) { e[o] = expf(e[o] - mx); sum += e[o]; }
      float inv = 1.f / sum;
#pragma unroll
      for (int o = 0; o < 10; ++o) cij[t*10 + o] = e[o] * inv;
    }
    __syncthreads();
    if (t < 160) {
      const int o = t >> 4;
      float s = cb[t];
      for (int i = 0; i < 64; ++i) s = fmaf(cij[i*10 + o], uh[i*160 + t], s);
      float d = s*s;
      d += __shfl_xor(d, 1); d += __shfl_xor(d, 2);
      d += __shfl_xor(d, 4); d += __shfl_xor(d, 8);
      float sc = d / (1.f + d) / sqrtf(d + EPSF);
      vv[t] = s * sc;
      if (r == 2 && (t & 15) == 0)
        vlen[b*10 + o] = sqrtf(sc*sc*d + EPSF);
    }
    __syncthreads();
    if (r < 2) {
      for (int f = t; f < 640; f += 256) {
        int i = f / 10, o = f % 10;
        const float* up = &uh[i*160 + o*16];
        const float* vp = &vv[o*16];
        float a = 0.f;
#pragma unroll
        for (int j = 0; j < 16; ++j) a = fmaf(up[j], vp[j], a);
        bij[f] += a;
      }
      __syncthreads();
    }
  }
  const int yb = y[b];
  const float* vy = &vv[yb*16];
  for (int nn = t; nn < 512; nn += 256) {
    float s = fc1b[nn];
#pragma unroll
    for (int k = 0; k < 16; ++k)
      s = fmaf(vy[k], fc1wt[(yb*16 + k)*512 + nn], s);   // coalesced rows
    h1f[b*512 + nn] = __float2bfloat16(fmaxf(s, 0.f));
  }
}

// ============================================================================
// fc_mfma: out = act(A[M,K]bf16 @ W[N,K]bf16^T + bias). Pure-register GEMM,
// two statically-indexed register sets (R5 scratch-demotion lesson).
// ============================================================================
template<int ACT, int MT, int NT>
__global__ __launch_bounds__(256) void fc_mfma_kernel(
    const __hip_bfloat16* __restrict__ A,   // [M,K]
    const __hip_bfloat16* __restrict__ W,   // [N,K]
    const float* __restrict__ bias,
    void* __restrict__ outv, int M, int N, int K)
{
  const int t    = threadIdx.x;
  const int lane = t & 63;
  const int w    = t >> 6;
  const int wr   = w >> 1, wc = w & 1;
  const int n    = lane & 15, g = lane >> 4;
  const int m0   = blockIdx.x * (2*MT*16) + wr*(MT*16);
  const int n0   = blockIdx.y * (2*NT*16) + wc*(NT*16);
  const __hip_bfloat16* Ap = A + (size_t)(m0 + n)*K + g*8;
  const __hip_bfloat16* Wp = W + (size_t)(n0 + n)*K + g*8;
  const int steps = K >> 5;

  bhalf8 aa0[MT], aa1[MT], bb0[NT], bb1[NT];
#pragma unroll
  for (int mt = 0; mt < MT; ++mt) {
    aa0[mt] = *(const bhalf8*)(Ap + (size_t)mt*16*K);
    aa1[mt] = *(const bhalf8*)(Ap + (size_t)mt*16*K + 32);
  }
#pragma unroll
  for (int nt = 0; nt < NT; ++nt) {
    bb0[nt] = *(const bhalf8*)(Wp + (size_t)nt*16*K);
    bb1[nt] = *(const bhalf8*)(Wp + (size_t)nt*16*K + 32);
  }

  floatx4 acc[MT][NT];
#pragma unroll
  for (int mt = 0; mt < MT; ++mt)
#pragma unroll
    for (int nt = 0; nt < NT; ++nt)
      acc[mt][nt] = (floatx4){0.f, 0.f, 0.f, 0.f};

#pragma unroll 1
  for (int s = 0; s < steps; s += 2) {
#pragma unroll
    for (int mt = 0; mt < MT; ++mt)
#pragma unroll
      for (int nt = 0; nt < NT; ++nt)
        acc[mt][nt] = __builtin_amdgcn_mfma_f32_16x16x32_bf16(
            aa0[mt], bb0[nt], acc[mt][nt], 0, 0, 0);
    {
      const int spre = (s + 2 < steps) ? (s + 2) : s;
#pragma unroll
      for (int mt = 0; mt < MT; ++mt)
        aa0[mt] = *(const bhalf8*)(Ap + (size_t)mt*16*K + spre*32);
#pragma unroll
      for (int nt = 0; nt < NT; ++nt)
        bb0[nt] = *(const bhalf8*)(Wp + (size_t)nt*16*K + spre*32);
    }
#pragma unroll
    for (int mt = 0; mt < MT; ++mt)
#pragma unroll
      for (int nt = 0; nt < NT; ++nt)
        acc[mt][nt] = __builtin_amdgcn_mfma_f32_16x16x32_bf16(
            aa1[mt], bb1[nt], acc[mt][nt], 0, 0, 0);
    {
      const int spre = (s + 3 < steps) ? (s + 3) : (s + 1);
#pragma unroll
      for (int mt = 0; mt < MT; ++mt)
        aa1[mt] = *(const bhalf8*)(Ap + (size_t)mt*16*K + spre*32);
#pragma unroll
      for (int nt = 0; nt < NT; ++nt)
        bb1[nt] = *(const bhalf8*)(Wp + (size_t)nt*16*K + spre*32);
    }
  }

  // epilogue: D row = g*4+r, col = n
#pragma unroll
  for (int mt = 0; mt < MT; ++mt) {
#pragma unroll
    for (int r = 0; r < 4; ++r) {
      const int m = m0 + mt*16 + g*4 + r;
#pragma unroll
      for (int nt = 0; nt < NT; ++nt) {
        const int col = n0 + nt*16 + n;
        float v = acc[mt][nt][r] + bias[col];
        if (ACT == 0) {
          ((__hip_bfloat16*)outv)[(size_t)m*N + col] =
              __float2bfloat16(fmaxf(v, 0.f));
        } else {
          ((float*)outv)[(size_t)m*N + col] = 1.f / (1.f + expf(-v));
        }
      }
    }
  }
}

// ============================================================================
extern "C" void kernel_launch(void* const* d_in, const int* in_sizes, int n_in,
                              void* d_out, int out_size, void* d_ws, size_t ws_size,
                              hipStream_t stream) {
  const float* x       = (const float*)d_in[0];
  const int*   y       = (const int*)  d_in[1];
  const float* conv1_w = (const float*)d_in[2];
  const float* conv1_b = (const float*)d_in[3];
  const float* conv2_w = (const float*)d_in[4];
  const float* conv2_b = (const float*)d_in[5];
  const float* conv3_w = (const float*)d_in[6];
  const float* conv3_b = (const float*)d_in[7];
  const float* caps_w  = (const float*)d_in[8];
  const float* caps_b  = (const float*)d_in[9];
  const float* fc1_w   = (const float*)d_in[10];
  const float* fc1_b   = (const float*)d_in[11];
  const float* fc2_w   = (const float*)d_in[12];
  const float* fc2_b   = (const float*)d_in[13];
  const float* fc3_w   = (const float*)d_in[14];
  const float* fc3_b   = (const float*)d_in[15];
  float* out = (float*)d_out;
  float* ws  = (float*)d_ws;

  // ws layout (float units), total 24,526,848 floats = 98.1 MB
  __hip_bfloat16* h1t   = (__hip_bfloat16*)ws;                // 29,491,200 bf16
  __hip_bfloat16* wt2   = (__hip_bfloat16*)(ws + 14745600);   //    819,200 bf16
  __hip_bfloat16* wt3   = (__hip_bfloat16*)(ws + 15155200);   //  1,638,400 bf16
  __hip_bfloat16* h2t   = (__hip_bfloat16*)(ws + 15974400);   //  9,437,184 bf16
  float*          h3c   = ws + 20692992;                      //  1,048,576 f32
  __hip_bfloat16* h1f   = (__hip_bfloat16*)(ws + 21741568);   //    524,288 bf16
  __hip_bfloat16* h2f   = (__hip_bfloat16*)(ws + 22003712);   //  1,048,576 bf16
  __hip_bfloat16* wf2   = (__hip_bfloat16*)(ws + 22528000);   //    524,288 bf16
  __hip_bfloat16* wf3   = (__hip_bfloat16*)(ws + 22790144);   //  3,145,728 bf16
  __hip_bfloat16* cwt   = (__hip_bfloat16*)(ws + 24363008);   //    163,840 bf16
  float*          fc1wt = ws + 24444928;                      //     81,920 f32

  wtrans_kernel     <<<dim3(3200),  256, 0, stream>>>(conv2_w, wt2);
  wtrans3_kernel    <<<dim3(6400),  256, 0, stream>>>(conv3_w, wt3);
  wtrans_caps_kernel<<<dim3(640),   256, 0, stream>>>(caps_w, cwt);
  wtrans_fc1_kernel <<<dim3(320),   256, 0, stream>>>(fc1_w, fc1wt);
  cast_bf16_kernel  <<<dim3(2048),  256, 0, stream>>>(fc2_w, wf2, 524288);
  cast_bf16_kernel  <<<dim3(12288), 256, 0, stream>>>(fc3_w, wf3, 3145728);
  conv1_kernel<<<dim3(1024),      256, 0, stream>>>(x, conv1_w, conv1_b, h1t);
  conv2_mfma_kernel<<<dim3(512),  512, 0, stream>>>(h1t, wt2, conv2_b, h2t);
  conv3_mfma_kernel<<<dim3(256),  512, 0, stream>>>(h2t, wt3, conv3_b, h3c);
  caps_kernel<<<dim3(1024),       256, 0, stream>>>(h3c, cwt, caps_b, y,
                                                    fc1wt, fc1_b, out, h1f);
  fc_mfma_kernel<0,2,2><<<dim3(16, 16), 256, 0, stream>>>(
      h1f, wf2, fc2_b, h2f, 1024, 1024, 512);
  fc_mfma_kernel<1,2,2><<<dim3(16, 48), 256, 0, stream>>>(
      h2f, wf3, fc3_b, out + 10240, 1024, 3072, 1024);
}